// Round 10
// baseline (884.924 us; speedup 1.0000x reference)
//
#include <hip/hip_runtime.h>
#include <cmath>

#define C    128
#define GRID 1024
#define BLK  256

typedef __bf16 bf16x8 __attribute__((ext_vector_type(8)));
typedef float  f32x4  __attribute__((ext_vector_type(4)));
typedef unsigned short u16x8 __attribute__((ext_vector_type(8)));

// fp32 -> bf16 bits, round-to-nearest-even
static __device__ __forceinline__ unsigned short f2b(float f) {
    unsigned int u = __builtin_bit_cast(unsigned int, f);
    u += 0x7FFFu + ((u >> 16) & 1u);
    return (unsigned short)(u >> 16);
}
// bf16 bits -> fp32
static __device__ __forceinline__ float b2f(unsigned short u) {
    return __builtin_bit_cast(float, (unsigned int)u << 16);
}

// Device-wide sense barrier. Co-residency is guaranteed by construction:
// GRID=1024 blocks, __launch_bounds__(256,4) => VGPR<=128 and LDS 16.7KB
// => >=4 blocks/CU on 256 CUs => all 1024 blocks resident simultaneously.
static __device__ __forceinline__ void gsync(int* bar) {
    __syncthreads();
    if (threadIdx.x == 0) {
        __threadfence();   // release: flush this XCD's dirty L2 lines
        int g0 = __hip_atomic_load(bar + 1, __ATOMIC_RELAXED, __HIP_MEMORY_SCOPE_AGENT);
        int a  = __hip_atomic_fetch_add(bar, 1, __ATOMIC_ACQ_REL, __HIP_MEMORY_SCOPE_AGENT);
        if (a == GRID - 1) {
            __hip_atomic_store(bar, 0, __ATOMIC_RELAXED, __HIP_MEMORY_SCOPE_AGENT);
            __hip_atomic_fetch_add(bar + 1, 1, __ATOMIC_RELEASE, __HIP_MEMORY_SCOPE_AGENT);
        } else {
            while (__hip_atomic_load(bar + 1, __ATOMIC_ACQUIRE, __HIP_MEMORY_SCOPE_AGENT) == g0)
                __builtin_amdgcn_s_sleep(8);
        }
        __threadfence();   // acquire: invalidate L1/L2 before fresh reads
    }
    __syncthreads();
}

// ---------------------------------------------------------------------------
// One persistent kernel, 6 phases separated by grid barriers:
//  P0: in-degree counts (4 edges/thr, int atomics) + W pack (last 16 blocks)
//  P1: per-block 64-elem scan of counts (wave 0 of first SB blocks)  AND
//      MFMA GEMM yl = x@Wl^T, yr = x@Wr^T + b (bf16 out, LDS-transposed
//      coalesced epilogue), grid-strided over 16-node tiles
//  P2: block 0 scans the 1024 block partials (int4 + shfl)
//  P3: cursor[idx] = global exclusive prefix
//  P4: CSR fill (atomic cursor advance; cursor becomes inclusive end)
//  P5: out = mean_gather(yl) + yr -> log_softmax (wave/node, grid-strided)
// ---------------------------------------------------------------------------
__global__ __launch_bounds__(BLK, 4)
void sage_mega(const float* __restrict__ x, const int* __restrict__ ei,
               const float* __restrict__ Wl, const float* __restrict__ Wr,
               const float* __restrict__ bias,
               int* counts, int* partials, int* bar, int* cursor, int* csr,
               unsigned short* yl, unsigned short* yr, unsigned short* wp,
               float* __restrict__ out, int N, int E) {
    __shared__ float st[16][260];   // GEMM epilogue transpose (16.6 KB)
    __shared__ int wsum[4];

    const int bid  = blockIdx.x;
    const int t    = threadIdx.x;
    const int gtid = bid * BLK + t;
    const int l = t & 63;
    const int w = t >> 6;
    const int g = l >> 4;

    // ================= P0: degree count + W pack =================
    {
        int e = gtid * 4;
        if (e + 3 < E) {
            int4 d = *(const int4*)(ei + E + e);
            atomicAdd(&counts[d.x], 1);
            atomicAdd(&counts[d.y], 1);
            atomicAdd(&counts[d.z], 1);
            atomicAdd(&counts[d.w], 1);
        } else {
            for (; e < E; ++e) atomicAdd(&counts[ei[E + e]], 1);
        }
        if (bid >= GRID - 16) {
            // pack B = [Wl | Wr] (K=128 x N=256) in MFMA fragment order:
            // frag f = kt*16 + c, lane ll, elem j: k = kt*32+(ll>>4)*8+j,
            // n = c*16+(ll&15); B(k,n) = n<128 ? Wl[n][k] : Wr[n-128][k].
            int s = (bid - (GRID - 16)) * BLK + t;   // 0..4095
            int f = s >> 6, ll = s & 63;
            int kt = f >> 4, c = f & 15;
            int gg = ll >> 4;
            int n = c * 16 + (ll & 15);
            const float* src = (n < C) ? (Wl + (size_t)n * C)
                                       : (Wr + (size_t)(n - C) * C);
            u16x8 o;
#pragma unroll
            for (int j = 0; j < 8; ++j) o[j] = f2b(src[kt * 32 + gg * 8 + j]);
            *(u16x8*)(wp + (size_t)s * 8) = o;
        }
    }
    gsync(bar);

    // ====== P1: local scan (wave 0 of first SB blocks) + GEMM ======
    const int SB = (N + 63) >> 6;
    int inc = 0, cval = 0;
    if (w == 0 && bid < SB) {
        int idx = bid * 64 + l;
        cval = (idx < N) ? counts[idx] : 0;
        inc = cval;
#pragma unroll
        for (int off = 1; off < 64; off <<= 1) {
            int v = __shfl_up(inc, off);
            if (l >= off) inc += v;
        }
        if (l == 63) partials[bid] = inc;
    }

    {
        const bf16x8* B = (const bf16x8*)wp;
        const int NT = (N + 15) >> 4;
        for (int tile = bid; tile < NT; tile += GRID) {
            int base = tile * 16;
            int node = base + (l & 15);
            if (node >= N) node = N - 1;
            const float4* xv = (const float4*)(x + (size_t)node * C);
            f32x4 acc0 = {0.f,0.f,0.f,0.f}, acc1 = {0.f,0.f,0.f,0.f};
            f32x4 acc2 = {0.f,0.f,0.f,0.f}, acc3 = {0.f,0.f,0.f,0.f};
#pragma unroll
            for (int kt = 0; kt < 4; ++kt) {
                float4 xa = xv[kt * 8 + g * 2];
                float4 xc = xv[kt * 8 + g * 2 + 1];
                u16x8 ab;
                ab[0]=f2b(xa.x); ab[1]=f2b(xa.y); ab[2]=f2b(xa.z); ab[3]=f2b(xa.w);
                ab[4]=f2b(xc.x); ab[5]=f2b(xc.y); ab[6]=f2b(xc.z); ab[7]=f2b(xc.w);
                bf16x8 af = __builtin_bit_cast(bf16x8, ab);
                int c = w * 4;
                bf16x8 b0 = B[(size_t)(kt * 16 + c + 0) * 64 + l];
                bf16x8 b1 = B[(size_t)(kt * 16 + c + 1) * 64 + l];
                bf16x8 b2 = B[(size_t)(kt * 16 + c + 2) * 64 + l];
                bf16x8 b3 = B[(size_t)(kt * 16 + c + 3) * 64 + l];
                acc0 = __builtin_amdgcn_mfma_f32_16x16x32_bf16(af, b0, acc0, 0,0,0);
                acc1 = __builtin_amdgcn_mfma_f32_16x16x32_bf16(af, b1, acc1, 0,0,0);
                acc2 = __builtin_amdgcn_mfma_f32_16x16x32_bf16(af, b2, acc2, 0,0,0);
                acc3 = __builtin_amdgcn_mfma_f32_16x16x32_bf16(af, b3, acc3, 0,0,0);
            }
            // D layout (verified m89): col = l&15, row = g*4 + reg.
            __syncthreads();
            {
                int cb = w * 4, cc = l & 15;
#pragma unroll
                for (int r = 0; r < 4; ++r) st[g*4+r][(cb+0)*16+cc] = acc0[r];
#pragma unroll
                for (int r = 0; r < 4; ++r) st[g*4+r][(cb+1)*16+cc] = acc1[r];
#pragma unroll
                for (int r = 0; r < 4; ++r) st[g*4+r][(cb+2)*16+cc] = acc2[r];
#pragma unroll
                for (int r = 0; r < 4; ++r) st[g*4+r][(cb+3)*16+cc] = acc3[r];
            }
            __syncthreads();
            {
                int row = t >> 4;
                int f0 = (t & 15) * 8;
                if (base + row < N) {
                    u16x8 o;
#pragma unroll
                    for (int j = 0; j < 8; ++j) o[j] = f2b(st[row][f0 + j]);
                    *(u16x8*)(yl + (size_t)(base + row) * C + f0) = o;
                    float4 bv0 = *(const float4*)(bias + f0);
                    float4 bv1 = *(const float4*)(bias + f0 + 4);
                    float bb[8] = {bv0.x,bv0.y,bv0.z,bv0.w,bv1.x,bv1.y,bv1.z,bv1.w};
                    u16x8 o2;
#pragma unroll
                    for (int j = 0; j < 8; ++j) o2[j] = f2b(st[row][C + f0 + j] + bb[j]);
                    *(u16x8*)(yr + (size_t)(base + row) * C + f0) = o2;
                }
            }
        }
    }
    gsync(bar);

    // ====== P2: block 0 scans partials[GRID] ======
    if (bid == 0) {
        int4 v = ((const int4*)partials)[t];
        int tot = v.x + v.y + v.z + v.w;
        int it = tot;
#pragma unroll
        for (int off = 1; off < 64; off <<= 1) {
            int u = __shfl_up(it, off);
            if (l >= off) it += u;
        }
        if (l == 63) wsum[w] = it;
        __syncthreads();
        int add = 0;
#pragma unroll
        for (int j = 0; j < 4; ++j)
            if (j < w) add += wsum[j];
        int ex = add + it - tot;
        int4 o;
        o.x = ex;
        o.y = ex + v.x;
        o.z = ex + v.x + v.y;
        o.w = ex + v.x + v.y + v.z;
        ((int4*)partials)[t] = o;
    }
    gsync(bar);

    // ====== P3: write cursor (global exclusive starts) ======
    if (w == 0 && bid < SB) {
        int idx = bid * 64 + l;
        if (idx < N) cursor[idx] = partials[bid] + inc - cval;
    }
    gsync(bar);

    // ====== P4: fill CSR (cursor -> inclusive ends) ======
    {
        int e = gtid * 4;
        if (e + 3 < E) {
            int4 sv = *(const int4*)(ei + e);
            int4 dv = *(const int4*)(ei + E + e);
            csr[atomicAdd(&cursor[dv.x], 1)] = sv.x;
            csr[atomicAdd(&cursor[dv.y], 1)] = sv.y;
            csr[atomicAdd(&cursor[dv.z], 1)] = sv.z;
            csr[atomicAdd(&cursor[dv.w], 1)] = sv.w;
        } else {
            for (; e < E; ++e) {
                int pos = atomicAdd(&cursor[ei[E + e]], 1);
                csr[pos] = ei[e];
            }
        }
    }
    gsync(bar);

    // ====== P5: mean-gather(yl) + yr -> log_softmax ======
    {
        const int q = g;          // quarter: neighbor residues q (mod 4)
        const int fl = l & 15;    // 16B slot within the 256B row
        const int NG = (N + 3) >> 2;
        for (int grp = bid; grp < NG; grp += GRID) {
            int node = grp * 4 + w;
            if (node < N) {
                int p0 = (node == 0) ? 0 : cursor[node - 1];
                int p1 = cursor[node];
                int deg = p1 - p0;
                float a[8];
#pragma unroll
                for (int j = 0; j < 8; ++j) a[j] = 0.f;
                int p = p0 + q;
                for (; p + 12 < p1; p += 16) {
                    int s0 = csr[p], s1 = csr[p + 4], s2 = csr[p + 8], s3 = csr[p + 12];
                    u16x8 v0 = *(const u16x8*)(yl + (size_t)s0 * C + fl * 8);
                    u16x8 v1 = *(const u16x8*)(yl + (size_t)s1 * C + fl * 8);
                    u16x8 v2 = *(const u16x8*)(yl + (size_t)s2 * C + fl * 8);
                    u16x8 v3 = *(const u16x8*)(yl + (size_t)s3 * C + fl * 8);
#pragma unroll
                    for (int j = 0; j < 8; ++j)
                        a[j] += (b2f(v0[j]) + b2f(v1[j])) + (b2f(v2[j]) + b2f(v3[j]));
                }
                for (; p + 4 < p1; p += 8) {
                    int s0 = csr[p], s1 = csr[p + 4];
                    u16x8 v0 = *(const u16x8*)(yl + (size_t)s0 * C + fl * 8);
                    u16x8 v1 = *(const u16x8*)(yl + (size_t)s1 * C + fl * 8);
#pragma unroll
                    for (int j = 0; j < 8; ++j) a[j] += b2f(v0[j]) + b2f(v1[j]);
                }
                if (p < p1) {
                    int s0 = csr[p];
                    u16x8 v0 = *(const u16x8*)(yl + (size_t)s0 * C + fl * 8);
#pragma unroll
                    for (int j = 0; j < 8; ++j) a[j] += b2f(v0[j]);
                }
#pragma unroll
                for (int j = 0; j < 8; ++j) {
                    a[j] += __shfl_xor(a[j], 16);
                    a[j] += __shfl_xor(a[j], 32);
                }
                if (q == 0) {
                    float inv = 1.0f / fmaxf((float)deg, 1.0f);
                    u16x8 yv = *(const u16x8*)(yr + (size_t)node * C + fl * 8);
#pragma unroll
                    for (int j = 0; j < 8; ++j) a[j] = a[j] * inv + b2f(yv[j]);
                    float m = a[0];
#pragma unroll
                    for (int j = 1; j < 8; ++j) m = fmaxf(m, a[j]);
#pragma unroll
                    for (int off = 1; off < 16; off <<= 1)
                        m = fmaxf(m, __shfl_xor(m, off));
                    float s = 0.f;
#pragma unroll
                    for (int j = 0; j < 8; ++j) s += expf(a[j] - m);
#pragma unroll
                    for (int off = 1; off < 16; off <<= 1)
                        s += __shfl_xor(s, off);
                    float ls = m + logf(s);
                    float4 o0, o1;
                    o0.x = a[0] - ls; o0.y = a[1] - ls; o0.z = a[2] - ls; o0.w = a[3] - ls;
                    o1.x = a[4] - ls; o1.y = a[5] - ls; o1.z = a[6] - ls; o1.w = a[7] - ls;
                    float4* op = (float4*)(out + (size_t)node * C + fl * 8);
                    op[0] = o0;
                    op[1] = o1;
                }
            }
        }
    }
}

extern "C" void kernel_launch(void* const* d_in, const int* in_sizes, int n_in,
                              void* d_out, int out_size, void* d_ws, size_t ws_size,
                              hipStream_t stream) {
    const float* x  = (const float*)d_in[0];
    const int*   ei = (const int*)d_in[1];
    const float* Wl = (const float*)d_in[2];
    const float* Wr = (const float*)d_in[3];
    const float* b  = (const float*)d_in[4];
    float* out = (float*)d_out;

    const int N = in_sizes[0] / C;   // 50000
    const int E = in_sizes[1] / 2;   // 600000

    // ws layout (all 16B-aligned): ~28.5 MB total
    int* counts   = (int*)d_ws;                    // N
    int* partials = counts + N;                    // GRID
    int* bar      = partials + GRID;               // 8 (barrier state)
    int* cursor   = bar + 8;                       // N
    int* csr      = cursor + N;                    // E
    unsigned short* yl = (unsigned short*)(csr + E);   // N*C bf16
    unsigned short* yr = yl + (size_t)N * C;           // N*C bf16
    unsigned short* wp = yr + (size_t)N * C;           // 128*256 bf16 pack

    hipMemsetAsync(counts, 0, (size_t)(N + GRID + 8) * sizeof(int), stream);
    sage_mega<<<GRID, BLK, 0, stream>>>(x, ei, Wl, Wr, b, counts, partials, bar,
                                        cursor, csr, yl, yr, wp, out, N, E);
}

// Round 11
// 152.434 us; speedup vs baseline: 5.8053x; 5.8053x over previous
//
#include <hip/hip_runtime.h>
#include <cmath>

#define C 128     // in/out channels

typedef __bf16 bf16x8 __attribute__((ext_vector_type(8)));
typedef float  f32x4  __attribute__((ext_vector_type(4)));
typedef unsigned short u16x8 __attribute__((ext_vector_type(8)));

// fp32 -> bf16 bits, round-to-nearest-even
static __device__ __forceinline__ unsigned short f2b(float f) {
    unsigned int u = __builtin_bit_cast(unsigned int, f);
    u += 0x7FFFu + ((u >> 16) & 1u);
    return (unsigned short)(u >> 16);
}
// bf16 bits -> fp32
static __device__ __forceinline__ float b2f(unsigned short u) {
    return __builtin_bit_cast(float, (unsigned int)u << 16);
}

// ---------------------------------------------------------------------------
// Zero the counts array (HIP's fill kernel is launch-latency overhead).
// ---------------------------------------------------------------------------
__global__ __launch_bounds__(256)
void sage_zero(int4* __restrict__ p, int n4) {
    int i = blockIdx.x * blockDim.x + threadIdx.x;
    if (i < n4) p[i] = make_int4(0, 0, 0, 0);
}

// ---------------------------------------------------------------------------
// Prep kernel, role by block range:
//  [0, CB)   : in-degree counts, 8 edges/thread (int atomics)
//  [CB,+16)  : pack B = [Wl | Wr] (K=128 x N=256) into MFMA-fragment order:
//              frag f = kt*16 + c, lane l, elem j: k = kt*32+(l>>4)*8+j,
//              n = c*16+(l&15); B(k,n) = n<128 ? Wl[n][k] : Wr[n-128][k].
// ---------------------------------------------------------------------------
__global__ __launch_bounds__(256)
void sage_prep(const int* __restrict__ ei, const float* __restrict__ Wl,
               const float* __restrict__ Wr, int* __restrict__ counts,
               unsigned short* __restrict__ wp, int E, int CB) {
    int bid = blockIdx.x;
    int t = threadIdx.x;
    if (bid < CB) {
        int e = (bid * 256 + t) * 8;
        if (e + 7 < E) {
            int4 d0 = *(const int4*)(ei + E + e);
            int4 d1 = *(const int4*)(ei + E + e + 4);
            atomicAdd(&counts[d0.x], 1);
            atomicAdd(&counts[d0.y], 1);
            atomicAdd(&counts[d0.z], 1);
            atomicAdd(&counts[d0.w], 1);
            atomicAdd(&counts[d1.x], 1);
            atomicAdd(&counts[d1.y], 1);
            atomicAdd(&counts[d1.z], 1);
            atomicAdd(&counts[d1.w], 1);
        } else {
            for (; e < E; ++e) atomicAdd(&counts[ei[E + e]], 1);
        }
    } else {
        int s = (bid - CB) * 256 + t;        // 0..4095
        int f = s >> 6, l = s & 63;
        int kt = f >> 4, c = f & 15;
        int g = l >> 4;
        int n = c * 16 + (l & 15);
        const float* src = (n < C) ? (Wl + (size_t)n * C)
                                   : (Wr + (size_t)(n - C) * C);
        u16x8 o;
#pragma unroll
        for (int j = 0; j < 8; ++j) o[j] = f2b(src[kt * 32 + g * 8 + j]);
        *(u16x8*)(wp + (size_t)s * 8) = o;
    }
}

// ---------------------------------------------------------------------------
// GEMM + scan dispatch.
//  block 0          : 256-thread exclusive scan of counts -> cursor
//  blocks 1..NT     : MFMA GEMM tile (16 nodes): yl = x@Wl^T, yr = x@Wr^T+b,
//                     bf16 out via LDS-transpose epilogue (coalesced 16B/lane
//                     stores — fixes r9's scattered-2B-store regression).
// Scan overlaps the GEMM blocks, hiding its latency entirely.
// ---------------------------------------------------------------------------
__global__ __launch_bounds__(256)
void sage_gemm_scan(const float* __restrict__ x,
                    const unsigned short* __restrict__ wp,
                    const float* __restrict__ bias,
                    const int* __restrict__ counts, int* __restrict__ cursor,
                    unsigned short* __restrict__ yl,
                    unsigned short* __restrict__ yr, int N) {
    int bid = blockIdx.x;
    int t = threadIdx.x;

    if (bid == 0) {
        // ---- exclusive scan, 256 threads, CH ints each (CH % 4 == 0) ----
        __shared__ int part[256];
        const int CH = (((N + 255) >> 8) + 3) & ~3;
        int lo = t * CH;
        int s = 0;
        for (int i = 0; i < CH; i += 4) {
            int idx = lo + i;
            if (idx + 3 < N) {
                int4 v = *(const int4*)(counts + idx);
                s += v.x + v.y + v.z + v.w;
            } else {
                for (int k = idx; k < N && k < idx + 4; ++k) s += counts[k];
            }
        }
        part[t] = s;
        __syncthreads();
        for (int off = 1; off < 256; off <<= 1) {
            int v = (t >= off) ? part[t - off] : 0;
            __syncthreads();
            part[t] += v;
            __syncthreads();
        }
        int run = (t == 0) ? 0 : part[t - 1];
        for (int i = 0; i < CH; i += 4) {
            int idx = lo + i;
            if (idx + 3 < N) {
                int4 v = *(const int4*)(counts + idx);
                int4 o;
                o.x = run; run += v.x;
                o.y = run; run += v.y;
                o.z = run; run += v.z;
                o.w = run; run += v.w;
                *(int4*)(cursor + idx) = o;
            } else {
                for (int k = idx; k < N && k < idx + 4; ++k) {
                    cursor[k] = run;
                    run += counts[k];
                }
            }
        }
        return;
    }

    // ---- MFMA GEMM tile ----
    __shared__ float st[16][260];   // transpose staging (16.6 KB)

    int w = t >> 6, l = t & 63;
    int g = l >> 4;
    int base = (bid - 1) * 16;
    int node = base + (l & 15);
    if (node >= N) node = N - 1;

    const float4* xv = (const float4*)(x + (size_t)node * C);
    const bf16x8* B = (const bf16x8*)wp;

    f32x4 acc0 = {0.f,0.f,0.f,0.f}, acc1 = {0.f,0.f,0.f,0.f};
    f32x4 acc2 = {0.f,0.f,0.f,0.f}, acc3 = {0.f,0.f,0.f,0.f};

#pragma unroll
    for (int kt = 0; kt < 4; ++kt) {
        float4 xa = xv[kt * 8 + g * 2];
        float4 xc = xv[kt * 8 + g * 2 + 1];
        u16x8 ab;
        ab[0]=f2b(xa.x); ab[1]=f2b(xa.y); ab[2]=f2b(xa.z); ab[3]=f2b(xa.w);
        ab[4]=f2b(xc.x); ab[5]=f2b(xc.y); ab[6]=f2b(xc.z); ab[7]=f2b(xc.w);
        bf16x8 af = __builtin_bit_cast(bf16x8, ab);
        int c = w * 4;
        bf16x8 b0 = B[(size_t)(kt * 16 + c + 0) * 64 + l];
        bf16x8 b1 = B[(size_t)(kt * 16 + c + 1) * 64 + l];
        bf16x8 b2 = B[(size_t)(kt * 16 + c + 2) * 64 + l];
        bf16x8 b3 = B[(size_t)(kt * 16 + c + 3) * 64 + l];
        acc0 = __builtin_amdgcn_mfma_f32_16x16x32_bf16(af, b0, acc0, 0,0,0);
        acc1 = __builtin_amdgcn_mfma_f32_16x16x32_bf16(af, b1, acc1, 0,0,0);
        acc2 = __builtin_amdgcn_mfma_f32_16x16x32_bf16(af, b2, acc2, 0,0,0);
        acc3 = __builtin_amdgcn_mfma_f32_16x16x32_bf16(af, b3, acc3, 0,0,0);
    }

    // D layout (verified m89): col = l&15, row = g*4 + reg.
    {
        int cb = w * 4, cc = l & 15;
#pragma unroll
        for (int r = 0; r < 4; ++r) st[g*4+r][(cb+0)*16+cc] = acc0[r];
#pragma unroll
        for (int r = 0; r < 4; ++r) st[g*4+r][(cb+1)*16+cc] = acc1[r];
#pragma unroll
        for (int r = 0; r < 4; ++r) st[g*4+r][(cb+2)*16+cc] = acc2[r];
#pragma unroll
        for (int r = 0; r < 4; ++r) st[g*4+r][(cb+3)*16+cc] = acc3[r];
    }
    __syncthreads();
    {
        int row = t >> 4;
        int f0 = (t & 15) * 8;
        if (base + row < N) {
            u16x8 o;
#pragma unroll
            for (int j = 0; j < 8; ++j) o[j] = f2b(st[row][f0 + j]);
            *(u16x8*)(yl + (size_t)(base + row) * C + f0) = o;
            float4 bv0 = *(const float4*)(bias + f0);
            float4 bv1 = *(const float4*)(bias + f0 + 4);
            float bb[8] = {bv0.x,bv0.y,bv0.z,bv0.w,bv1.x,bv1.y,bv1.z,bv1.w};
            u16x8 o2;
#pragma unroll
            for (int j = 0; j < 8; ++j) o2[j] = f2b(st[row][C + f0 + j] + bb[j]);
            *(u16x8*)(yr + (size_t)(base + row) * C + f0) = o2;
        }
    }
}

// ---------------------------------------------------------------------------
// CSR fill: scatter src ids; cursor becomes inclusive scan (end offsets).
// ---------------------------------------------------------------------------
__global__ __launch_bounds__(256)
void sage_fill(const int* __restrict__ ei, int* __restrict__ cursor,
               int* __restrict__ csr, int E) {
    int i = blockIdx.x * blockDim.x + threadIdx.x;
    int e = i * 4;
    if (e + 3 < E) {
        int4 sv = *(const int4*)(ei + e);
        int4 dv = *(const int4*)(ei + E + e);
        csr[atomicAdd(&cursor[dv.x], 1)] = sv.x;
        csr[atomicAdd(&cursor[dv.y], 1)] = sv.y;
        csr[atomicAdd(&cursor[dv.z], 1)] = sv.z;
        csr[atomicAdd(&cursor[dv.w], 1)] = sv.w;
    } else {
        for (; e < E; ++e) {
            int pos = atomicAdd(&cursor[ei[E + e]], 1);
            csr[pos] = ei[e];
        }
    }
}

// ---------------------------------------------------------------------------
// Final: out = mean_gather(yl) + yr -> log_softmax. One wave per node, no
// LDS (full occupancy hides gather latency). Quarter-wave per neighbor row
// (16 lanes x 16 B = one 256 B bf16 row), 4-deep pipeline; cross-quarter
// shfl reduce; lanes 0-15 finish: 8 feats each, shfl-lsm, float4 writes.
// ---------------------------------------------------------------------------
__global__ __launch_bounds__(256)
void sage_final(const unsigned short* __restrict__ yl,
                const unsigned short* __restrict__ yr,
                const int* __restrict__ cursor, const int* __restrict__ csr,
                float* __restrict__ out, int N) {
    int wv = threadIdx.x >> 6;
    int node = blockIdx.x * 4 + wv;
    if (node >= N) return;
    int ln = threadIdx.x & 63;
    int q = ln >> 4;        // quarter: owns neighbor residues q (mod 4)
    int fl = ln & 15;       // 16B slot within the 256B row

    int p0 = (node == 0) ? 0 : cursor[node - 1];
    int p1 = cursor[node];
    int deg = p1 - p0;

    float a[8];
#pragma unroll
    for (int j = 0; j < 8; ++j) a[j] = 0.f;

    int p = p0 + q;
    for (; p + 12 < p1; p += 16) {
        int s0 = csr[p], s1 = csr[p + 4], s2 = csr[p + 8], s3 = csr[p + 12];
        u16x8 v0 = *(const u16x8*)(yl + (size_t)s0 * C + fl * 8);
        u16x8 v1 = *(const u16x8*)(yl + (size_t)s1 * C + fl * 8);
        u16x8 v2 = *(const u16x8*)(yl + (size_t)s2 * C + fl * 8);
        u16x8 v3 = *(const u16x8*)(yl + (size_t)s3 * C + fl * 8);
#pragma unroll
        for (int j = 0; j < 8; ++j)
            a[j] += (b2f(v0[j]) + b2f(v1[j])) + (b2f(v2[j]) + b2f(v3[j]));
    }
    for (; p + 4 < p1; p += 8) {
        int s0 = csr[p], s1 = csr[p + 4];
        u16x8 v0 = *(const u16x8*)(yl + (size_t)s0 * C + fl * 8);
        u16x8 v1 = *(const u16x8*)(yl + (size_t)s1 * C + fl * 8);
#pragma unroll
        for (int j = 0; j < 8; ++j) a[j] += b2f(v0[j]) + b2f(v1[j]);
    }
    if (p < p1) {
        int s0 = csr[p];
        u16x8 v0 = *(const u16x8*)(yl + (size_t)s0 * C + fl * 8);
#pragma unroll
        for (int j = 0; j < 8; ++j) a[j] += b2f(v0[j]);
    }

#pragma unroll
    for (int j = 0; j < 8; ++j) {
        a[j] += __shfl_xor(a[j], 16);
        a[j] += __shfl_xor(a[j], 32);
    }
    if (q != 0) return;

    float inv = 1.0f / fmaxf((float)deg, 1.0f);
    u16x8 yv = *(const u16x8*)(yr + (size_t)node * C + fl * 8);
#pragma unroll
    for (int j = 0; j < 8; ++j) a[j] = a[j] * inv + b2f(yv[j]);

    float m = a[0];
#pragma unroll
    for (int j = 1; j < 8; ++j) m = fmaxf(m, a[j]);
#pragma unroll
    for (int off = 1; off < 16; off <<= 1)
        m = fmaxf(m, __shfl_xor(m, off));
    float s = 0.f;
#pragma unroll
    for (int j = 0; j < 8; ++j) s += expf(a[j] - m);
#pragma unroll
    for (int off = 1; off < 16; off <<= 1)
        s += __shfl_xor(s, off);
    float ls = m + logf(s);

    float4 o0, o1;
    o0.x = a[0] - ls; o0.y = a[1] - ls; o0.z = a[2] - ls; o0.w = a[3] - ls;
    o1.x = a[4] - ls; o1.y = a[5] - ls; o1.z = a[6] - ls; o1.w = a[7] - ls;
    float4* op = (float4*)(out + (size_t)node * C + fl * 8);
    op[0] = o0;
    op[1] = o1;
}

extern "C" void kernel_launch(void* const* d_in, const int* in_sizes, int n_in,
                              void* d_out, int out_size, void* d_ws, size_t ws_size,
                              hipStream_t stream) {
    const float* x  = (const float*)d_in[0];
    const int*   ei = (const int*)d_in[1];
    const float* Wl = (const float*)d_in[2];
    const float* Wr = (const float*)d_in[3];
    const float* b  = (const float*)d_in[4];
    float* out = (float*)d_out;

    const int N = in_sizes[0] / C;   // 50000
    const int E = in_sizes[1] / 2;   // 600000

    // ws layout (all 16B-aligned): ~28.5 MB total
    int* counts = (int*)d_ws;                             // N
    int* cursor = counts + N;                             // N
    int* csr    = cursor + N;                             // E
    unsigned short* yl = (unsigned short*)(csr + E);      // N*C bf16
    unsigned short* yr = yl + (size_t)N * C;              // N*C bf16
    unsigned short* wp = yr + (size_t)N * C;              // 128*256 bf16 pack

    const int CB = (E + 2047) / 2048;        // count blocks (8 edges/thread)
    const int NT = (N + 15) / 16;            // GEMM tiles
    int eb4 = (E + 1023) / 1024;
    int n4 = (N + 3) / 4;

    sage_zero<<<(n4 + 255) / 256, 256, 0, stream>>>((int4*)counts, n4);
    sage_prep<<<CB + 16, 256, 0, stream>>>(ei, Wl, Wr, counts, wp, E, CB);
    sage_gemm_scan<<<NT + 1, 256, 0, stream>>>(x, wp, b, counts, cursor, yl, yr, N);
    sage_fill<<<eb4, 256, 0, stream>>>(ei, cursor, csr, E);
    sage_final<<<(N + 3) / 4, 256, 0, stream>>>(yl, yr, cursor, csr, out, N);
}